// Round 14
// baseline (99.842 us; speedup 1.0000x reference)
//
#include <hip/hip_runtime.h>
#include <math.h>

#define HH 512
#define WW 512
#define NB 8
#define NC 3
#define HW (HH*WW)

#define RSTRIP 8                          // output rows per wave
#define CSTRIP 54                         // output cols per wave (lanes 5..58)
#define NROWS (HH/RSTRIP)                 // 64
#define NCOLS ((WW + CSTRIP - 1)/CSTRIP)  // 10
#define WPB 4                             // waves per block

// ---- load own-column f32 for row RR into named regs (3 channels) ----
#define LOADR(RR, X0, X1, X2) do {                                            \
    const int r_ = (RR);                                                      \
    if ((unsigned)r_ < (unsigned)HH) {                                        \
        const size_t ro_ = (size_t)r_ * WW;                                   \
        X0 = inb ? ip0[ro_ + cxc] : 0.0f;                                     \
        X1 = inb ? ip1[ro_ + cxc] : 0.0f;                                     \
        X2 = inb ? ip2[ro_ + cxc] : 0.0f;                                     \
    } else { X0 = 0.0f; X1 = 0.0f; X2 = 0.0f; }                               \
} while (0)

// ---- H-blur for one channel: own value X, taps via shfl; -> hb[C][GP%9] ----
#define H1(GP, C, X) do {                                                     \
    float u4_ = __shfl_up(X, 4), u3_ = __shfl_up(X, 3);                       \
    float u2_ = __shfl_up(X, 2), u1_ = __shfl_up(X, 1);                       \
    float d1_ = __shfl_down(X, 1), d2_ = __shfl_down(X, 2);                   \
    float d3_ = __shfl_down(X, 3), d4_ = __shfl_down(X, 4);                   \
    double a_ = 0.0;                                                          \
    a_ = fma(g[0], (double)u4_, a_);                                          \
    a_ = fma(g[1], (double)u3_, a_);                                          \
    a_ = fma(g[2], (double)u2_, a_);                                          \
    a_ = fma(g[3], (double)u1_, a_);                                          \
    a_ = fma(g[4], (double)(X), a_);                                          \
    a_ = fma(g[5], (double)d1_, a_);                                          \
    a_ = fma(g[6], (double)d2_, a_);                                          \
    a_ = fma(g[7], (double)d3_, a_);                                          \
    a_ = fma(g[8], (double)d4_, a_);                                          \
    hb[C][(GP) % 9] = a_;                                                     \
} while (0)

// ---- one sobel channel: reads vb[C] slots gp,gp+1,gp+2 (mod 3) ----
#define SOB1(GP, C) {                                                         \
    double top_ = up_ ? vb[C][(GP) % 3]       : 0.0;                          \
    double mid_ =       vb[C][((GP) + 1) % 3];                                \
    double bot_ = dn_ ? vb[C][((GP) + 2) % 3] : 0.0;                          \
    double s_ = top_ + 2.0 * mid_ + bot_;                                     \
    double d_ = top_ - bot_;                                                  \
    double sL_ = __shfl_up(s_, 1), sR_ = __shfl_down(s_, 1);                  \
    double dL_ = __shfl_up(d_, 1), dR_ = __shfl_down(d_, 1);                  \
    sL_ = cml ? sL_ : 0.0;  sR_ = cmr ? sR_ : 0.0;                            \
    dL_ = cml ? dL_ : 0.0;  dR_ = cmr ? dR_ : 0.0;                            \
    double gx_ = sL_ - sR_;                                                   \
    double gy_ = dL_ + 2.0 * d_ + dR_;                                        \
    mag_ += sqrt(gx_ * gx_ + gy_ * gy_);                                      \
    sgx_ += gx_; sgy_ += gy_; }

// ---- full phase GP (literal): H(row R0-5+GP); V (GP>=8); S (GP>=10) ----
#define PH(GP, X0, X1, X2) do {                                               \
    H1(GP, 0, X0); H1(GP, 1, X1); H1(GP, 2, X2);                              \
    if ((GP) >= 8) {                                                          \
        _Pragma("unroll")                                                     \
        for (int c = 0; c < 3; ++c) {                                         \
            double acc_ = 0.0;                                                \
            _Pragma("unroll")                                                 \
            for (int k = 0; k < 9; ++k)                                       \
                acc_ = fma(g[k], hb[c][((GP) + 1 + k) % 9], acc_);            \
            vb[c][((GP) + 2) % 3] = acc_;                                     \
        }                                                                     \
    }                                                                         \
    if ((GP) >= 10) {                                                         \
        const int ri_ = R0 - 10 + (GP);                                       \
        const bool up_ = (ri_ >= 1), dn_ = (ri_ <= HH - 2);                   \
        double mag_ = 0.0, sgx_ = 0.0, sgy_ = 0.0;                            \
        SOB1(GP, 0) SOB1(GP, 1) SOB1(GP, 2)                                   \
        if (lane_out) {                                                       \
            size_t o_ = (size_t)b * HW + (size_t)ri_ * WW + cx;               \
            GM[o_] = (float)mag_;                                             \
            double ax_ = fabs(sgx_), ay_ = fabs(sgy_);                        \
            int kp_;                                                          \
            if (ay_ <= ax_ * t225)      kp_ = (sgx_ >= 0.0) ? 4 : 0;          \
            else if (ay_ >= ax_ * t675) kp_ = (sgy_ > 0.0) ? 6 : 2;           \
            else if (sgx_ > 0.0)        kp_ = (sgy_ > 0.0) ? 5 : 3;           \
            else                        kp_ = (sgy_ > 0.0) ? 7 : 1;           \
            KP[o_] = (unsigned char)kp_;                                      \
        } }                                                                   \
} while (0)

// K1: register row-streaming separable conv; one wave per 54x8 strip, 4 waves
// per block. Each lane loads only its OWN column f32 per row (3 loads/phase,
// coalesced 256B); the 9 H-taps come from __shfl of neighbor lanes (values
// bit-identical to the r7 gather: same img floats, same fma order; OOB taps
// contribute +0 either way). One-row-ahead prefetch costs 6 VGPRs and hides
// VMEM latency under ~600cy of f64 ring compute. f64 end-to-end; GM stored f32.
__global__ __launch_bounds__(256) void canny_gm_kernel(
    const float* __restrict__ img, const float* __restrict__ gwin,
    float* __restrict__ GM, unsigned char* __restrict__ KP)
{
    const int lane = threadIdx.x & 63;
    const int wv   = threadIdx.x >> 6;         // 0..3
    const int cs   = blockIdx.x % NCOLS;
    const int rs   = (blockIdx.x / NCOLS) * WPB + wv;
    const int b    = blockIdx.y;

    const int R0 = rs * RSTRIP;
    const int cx = cs * CSTRIP - 5 + lane;     // this lane's img/blur column

    double g[9];
#pragma unroll
    for (int k = 0; k < 9; ++k) g[k] = (double)gwin[k];

    const bool inb = ((unsigned)cx < (unsigned)WW);
    const int  cxc = cx < 0 ? 0 : (cx > WW - 1 ? WW - 1 : cx);
    const bool lane_out = (lane >= 5) && (lane <= 58) && (cx < WW);
    const bool cml = ((unsigned)(cx - 1) < (unsigned)WW);
    const bool cmr = ((unsigned)(cx + 1) < (unsigned)WW);

    const float* ip0 = img + ((size_t)b * NC + 0) * HW;
    const float* ip1 = img + ((size_t)b * NC + 1) * HW;
    const float* ip2 = img + ((size_t)b * NC + 2) * HW;

    double hb[3][9];   // h-blur ring: row R0-5+gp -> slot gp%9
    double vb[3][3];   // v-blur ring: rv = R0-9+gp -> slot (gp+2)%3
#pragma unroll
    for (int c = 0; c < 3; ++c) {
#pragma unroll
        for (int k = 0; k < 9; ++k) hb[c][k] = 0.0;
#pragma unroll
        for (int k = 0; k < 3; ++k) vb[c][k] = 0.0;
    }

    const double t225 = 0.41421356237309503;   // tan(22.5 deg)
    const double t675 = 2.414213562373095;     // tan(67.5 deg)

    float a0, a1, a2, b0, b1, b2;

    LOADR(R0 - 5, a0, a1, a2);
    LOADR(R0 - 4, b0, b1, b2);  PH(0,  a0, a1, a2);
    LOADR(R0 - 3, a0, a1, a2);  PH(1,  b0, b1, b2);
    LOADR(R0 - 2, b0, b1, b2);  PH(2,  a0, a1, a2);
    LOADR(R0 - 1, a0, a1, a2);  PH(3,  b0, b1, b2);
    LOADR(R0 + 0, b0, b1, b2);  PH(4,  a0, a1, a2);
    LOADR(R0 + 1, a0, a1, a2);  PH(5,  b0, b1, b2);
    LOADR(R0 + 2, b0, b1, b2);  PH(6,  a0, a1, a2);
    LOADR(R0 + 3, a0, a1, a2);  PH(7,  b0, b1, b2);
    LOADR(R0 + 4, b0, b1, b2);  PH(8,  a0, a1, a2);
    LOADR(R0 + 5, a0, a1, a2);  PH(9,  b0, b1, b2);
    LOADR(R0 + 6, b0, b1, b2);  PH(10, a0, a1, a2);
    LOADR(R0 + 7, a0, a1, a2);  PH(11, b0, b1, b2);
    LOADR(R0 + 8, b0, b1, b2);  PH(12, a0, a1, a2);
    LOADR(R0 + 9, a0, a1, a2);  PH(13, b0, b1, b2);
    LOADR(R0 +10, b0, b1, b2);  PH(14, a0, a1, a2);
    LOADR(R0 +11, a0, a1, a2);  PH(15, b0, b1, b2);
    LOADR(R0 +12, b0, b1, b2);  PH(16, a0, a1, a2);
                                PH(17, b0, b1, b2);
}

// K23 fused: per 32x32 tile, compute the 34x34 halo of CODE bytes into LDS
// (thin/threshold decisions in f64 from f32 GM -- exact), then hysteresis.
// code bit0: thin > 0.3 ; bit1: 0.1 <= thin <= 0.3
__global__ __launch_bounds__(256) void canny_thin_out_kernel(
    const float* __restrict__ GM, const unsigned char* __restrict__ KP,
    float* __restrict__ out)
{
    __shared__ unsigned char scode[34 * 35];

    const int tilesX = WW / 32;                 // 16
    const int tx0 = (blockIdx.x % tilesX) * 32;
    const int ty0 = (blockIdx.x / tilesX) * 32;
    const int b = blockIdx.y;
    const int t = threadIdx.x;

    // dr+1 per b (digits b7..b0): 0,0,0,1,2,2,2,1 ; dc+1: 2,1,0,0,0,1,2,2
    const int dr = (int)((0x00012221u >> (b * 4)) & 15u) - 1;
    const int dc = (int)((0x21000122u >> (b * 4)) & 15u) - 1;

    // ---- phase 1: codes for tile+halo (34x34 items, width-34 walk)
    {
        int r = t / 34, cc = t % 34, idx = t;
#pragma unroll
        for (int it = 0; it < 5; ++it) {
            if (idx < 34 * 34) {
                int gi = ty0 - 1 + r, gj = tx0 - 1 + cc;
                unsigned char code = 0;
                if ((unsigned)gi < (unsigned)HH && (unsigned)gj < (unsigned)WW) {
                    size_t p0 = (size_t)gi * WW + gj;
                    int kp = KP[(size_t)b * HW + p0];
                    int kn = (kp + 4) & 7;
                    int ni = gi + dr, nj = gj + dc;
                    bool nin = ((unsigned)ni < (unsigned)HH) && ((unsigned)nj < (unsigned)WW);
                    size_t pn = (size_t)ni * WW + nj;
                    double gmp  = (double)GM[(size_t)kp * HW + p0];
                    double gmn  = (double)GM[(size_t)kn * HW + p0];
                    double gmpn = nin ? (double)GM[(size_t)kp * HW + pn] : 0.0;
                    double gmnn = nin ? (double)GM[(size_t)kn * HW + pn] : 0.0;
                    double pos = gmp - gmpn;
                    double neg = gmn - gmnn;
                    double thin = (fmin(pos, neg) > 0.0) ? (double)GM[(size_t)b * HW + p0] : 0.0;
                    if (thin > 0.3) code |= 1;
                    if (thin >= 0.1 && thin <= 0.3) code |= 2;
                }
                scode[r * 35 + cc] = code;
            }
            idx += 256; r += 7; cc += 18;        // 256 = 7*34 + 18
            if (cc >= 34) { cc -= 34; ++r; }
        }
    }
    __syncthreads();

    // ---- phase 2: hysteresis + border zero, 4 px/thread
#pragma unroll
    for (int p = 0; p < 4; ++p) {
        int pix = t + p * 256;
        int i = pix >> 5, j = pix & 31;
        int gi = ty0 + i, gj = tx0 + j;
        float res = 0.0f;
        if (gi > 0 && gi < HH - 1 && gj > 0 && gj < WW - 1) {
            const unsigned char* sc = scode + (i + 1) * 35 + (j + 1);
            unsigned char c = *sc;
            if (c & 1) {
                res = 1.0f;
            } else if (c & 2) {
                int any = 0;
                any |= sc[-36] & 1; any |= sc[-35] & 1; any |= sc[-34] & 1;
                any |= sc[-1]  & 1; any |= sc[ 1]  & 1;
                any |= sc[ 34] & 1; any |= sc[ 35] & 1; any |= sc[ 36] & 1;
                if (any) res = 1.0f;
            }
        }
        out[(size_t)b * HW + (size_t)gi * WW + gj] = res;
    }
}

extern "C" void kernel_launch(void* const* d_in, const int* in_sizes, int n_in,
                              void* d_out, int out_size, void* d_ws, size_t ws_size,
                              hipStream_t stream) {
    const float* img  = (const float*)d_in[0];
    const float* gwin = (const float*)d_in[1];

    float* GM = (float*)d_ws;                                   // 8 MB
    unsigned char* KP = (unsigned char*)d_ws + (size_t)NB * HW * sizeof(float);
    float* out = (float*)d_out;

    dim3 g1(NCOLS * (NROWS / WPB), NB);   // (160, 8) = 1280 blocks x 256 thr
    canny_gm_kernel<<<g1, 256, 0, stream>>>(img, gwin, GM, KP);

    dim3 g2((WW / 32) * (HH / 32), NB);   // (256, 8) blocks x 256
    canny_thin_out_kernel<<<g2, 256, 0, stream>>>(GM, KP, out);
}

// Round 15
// 67.930 us; speedup vs baseline: 1.4698x; 1.4698x over previous
//
#include <hip/hip_runtime.h>
#include <math.h>

#define HH 512
#define WW 512
#define NB 8
#define NC 3
#define HW (HH*WW)

#define RSTRIP 8                          // output rows per wave
#define CSTRIP 62                         // output cols per wave
#define NROWS (HH/RSTRIP)                 // 64
#define NCOLS ((WW + CSTRIP - 1)/CSTRIP)  // 9
#define WPB 4                             // waves per block

typedef float float4u __attribute__((ext_vector_type(4), aligned(4)));

// K1: register row-streaming separable conv; one 64-lane wave per 62x8 strip,
// 4 independent waves/block — byte-identical to the proven r7 structure
// (50us, VGPR 84) except: (a) interior strips (csafe) load the 9 taps as
// 2x dwordx4 + 1 dword instead of 27 scalars (same values, same fma order);
// (b) GM stored f32 (f64 compute; store-rounding proven safe r8-r12).
__global__ __launch_bounds__(256) void canny_gm_kernel(
    const float* __restrict__ img, const float* __restrict__ gwin,
    float* __restrict__ GM, unsigned char* __restrict__ KP)
{
    const int lane = threadIdx.x & 63;
    const int wv   = threadIdx.x >> 6;         // 0..3
    const int cs   = blockIdx.x % NCOLS;
    const int rs   = (blockIdx.x / NCOLS) * WPB + wv;
    const int b    = blockIdx.y;

    const int R0 = rs * RSTRIP;
    const int cl = cs * CSTRIP - 1 + lane;     // this lane's blur column

    double g[9];
#pragma unroll
    for (int k = 0; k < 9; ++k) g[k] = (double)gwin[k];

    // 9-tap column window: clamped indices; mask folded into per-lane coeffs
    int cidx[9]; double gk[9];
#pragma unroll
    for (int k = 0; k < 9; ++k) {
        int cc = cl - 4 + k;
        bool m = ((unsigned)cc < (unsigned)WW);
        gk[k] = m ? g[k] : 0.0;                // 0*finite = +/-0 -> acc unchanged
        int cc2 = cc < 0 ? 0 : cc;
        cidx[k] = cc2 > (WW - 1) ? (WW - 1) : cc2;
    }
    const bool csafe = (cs >= 1) && (cs <= NCOLS - 2);   // cl-4..cl+4 in-image
    const bool lane_out = (lane >= 1) && (lane <= CSTRIP) && (cl < WW);
    const bool cml = ((unsigned)(cl - 1) < (unsigned)WW);
    const bool cmr = ((unsigned)(cl + 1) < (unsigned)WW);

    const float* ip0 = img + ((size_t)b * NC + 0) * HW;
    const float* ip1 = img + ((size_t)b * NC + 1) * HW;
    const float* ip2 = img + ((size_t)b * NC + 2) * HW;

    double hb[3][9];   // h-blur ring: slot = phase
    double vb[3][3];   // v-blur ring
#pragma unroll
    for (int c = 0; c < 3; ++c) {
#pragma unroll
        for (int k = 0; k < 9; ++k) hb[c][k] = 0.0;
#pragma unroll
        for (int k = 0; k < 3; ++k) vb[c][k] = 0.0;
    }

    const double t225 = 0.41421356237309503;   // tan(22.5 deg)
    const double t675 = 2.414213562373095;     // tan(67.5 deg)

    auto PHASE = [&](int r, int ph, bool doV, bool doS) {
        // ---- h-blur of img row r -> hb[c][ph] (zero outside image)
        if ((unsigned)r < (unsigned)HH) {
            const size_t ro = (size_t)r * WW;
            float v0[9], v1[9], v2[9];
            if (csafe) {
                const float* rp0 = ip0 + ro + (size_t)(cl - 4);
                const float* rp1 = ip1 + ro + (size_t)(cl - 4);
                const float* rp2 = ip2 + ro + (size_t)(cl - 4);
                float4u p0 = *(const float4u*)rp0, q0 = *(const float4u*)(rp0 + 4);
                float4u p1 = *(const float4u*)rp1, q1 = *(const float4u*)(rp1 + 4);
                float4u p2 = *(const float4u*)rp2, q2 = *(const float4u*)(rp2 + 4);
                v0[0]=p0[0]; v0[1]=p0[1]; v0[2]=p0[2]; v0[3]=p0[3];
                v0[4]=q0[0]; v0[5]=q0[1]; v0[6]=q0[2]; v0[7]=q0[3]; v0[8]=rp0[8];
                v1[0]=p1[0]; v1[1]=p1[1]; v1[2]=p1[2]; v1[3]=p1[3];
                v1[4]=q1[0]; v1[5]=q1[1]; v1[6]=q1[2]; v1[7]=q1[3]; v1[8]=rp1[8];
                v2[0]=p2[0]; v2[1]=p2[1]; v2[2]=p2[2]; v2[3]=p2[3];
                v2[4]=q2[0]; v2[5]=q2[1]; v2[6]=q2[2]; v2[7]=q2[3]; v2[8]=rp2[8];
            } else {
#pragma unroll
                for (int k = 0; k < 9; ++k) {
                    v0[k] = ip0[ro + cidx[k]];
                    v1[k] = ip1[ro + cidx[k]];
                    v2[k] = ip2[ro + cidx[k]];
                }
            }
            double a0 = 0.0, a1 = 0.0, a2 = 0.0;
#pragma unroll
            for (int k = 0; k < 9; ++k) {
                a0 = fma(gk[k], (double)v0[k], a0);
                a1 = fma(gk[k], (double)v1[k], a1);
                a2 = fma(gk[k], (double)v2[k], a2);
            }
            hb[0][ph] = a0; hb[1][ph] = a1; hb[2][ph] = a2;
        } else {
            hb[0][ph] = 0.0; hb[1][ph] = 0.0; hb[2][ph] = 0.0;
        }

        // ---- v-blur row rv = r-4 -> vb[c][(ph+2)%3]; tap r-8+k in slot (ph+1+k)%9
        if (doV) {
#pragma unroll
            for (int c = 0; c < 3; ++c) {
                double acc = 0.0;
#pragma unroll
                for (int k = 0; k < 9; ++k)
                    acc = fma(g[k], hb[c][(ph + 1 + k) % 9], acc);
                vb[c][(ph + 2) % 3] = acc;
            }
        }

        // ---- sobel + GM/sector at row ri = r-5
        if (doS) {
            const int ri = r - 5;
            const bool up = (ri >= 1), dn = (ri <= HH - 2);
            double mag = 0.0, sgx = 0.0, sgy = 0.0;
#pragma unroll
            for (int c = 0; c < 3; ++c) {
                double top = up ? vb[c][ph % 3]       : 0.0;  // row ri-1
                double mid =      vb[c][(ph + 1) % 3];        // row ri
                double bot = dn ? vb[c][(ph + 2) % 3] : 0.0;  // row ri+1
                double s = top + 2.0 * mid + bot;   // [1,2,1] column sum
                double d = top - bot;               // vertical diff
                double sL = __shfl_up(s, 1), sR = __shfl_down(s, 1);
                double dL = __shfl_up(d, 1), dR = __shfl_down(d, 1);
                sL = cml ? sL : 0.0;  sR = cmr ? sR : 0.0;
                dL = cml ? dL : 0.0;  dR = cmr ? dR : 0.0;
                double gx = sL - sR;
                double gy = dL + 2.0 * d + dR;
                mag += sqrt(gx * gx + gy * gy);
                sgx += gx; sgy += gy;
            }
            if (lane_out) {
                size_t o = (size_t)b * HW + (size_t)ri * WW + cl;
                GM[o] = (float)mag;
                double ax = fabs(sgx), ay = fabs(sgy);
                int kp;
                if (ay <= ax * t225)      kp = (sgx >= 0.0) ? 4 : 0;
                else if (ay >= ax * t675) kp = (sgy > 0.0) ? 6 : 2;
                else if (sgx > 0.0)       kp = (sgy > 0.0) ? 5 : 3;
                else                      kp = (sgy > 0.0) ? 7 : 1;
                KP[o] = (unsigned char)kp;
            }
        }
    };

    // chunk 0: rows R0-5 .. R0+3 — H; V starts at ph 8 (rv = R0-1)
    {
        const int rb = R0 - 5;
#pragma unroll
        for (int ph = 0; ph < 9; ++ph) PHASE(rb + ph, ph, ph == 8, false);
    }
    // chunk 1: rows R0+4 .. R0+12 — H+V; S from ph 1 (ri = R0 .. R0+7)
    {
        const int rb = R0 + 4;
#pragma unroll
        for (int ph = 0; ph < 9; ++ph) PHASE(rb + ph, ph, true, ph >= 1);
    }
}

// K23 fused: per 32x32 tile, compute the 34x34 halo of CODE bytes into LDS
// (thin/threshold decisions in f64 from f32 GM -- exact), then hysteresis.
// code bit0: thin > 0.3 ; bit1: 0.1 <= thin <= 0.3
__global__ __launch_bounds__(256) void canny_thin_out_kernel(
    const float* __restrict__ GM, const unsigned char* __restrict__ KP,
    float* __restrict__ out)
{
    __shared__ unsigned char scode[34 * 35];

    const int tilesX = WW / 32;                 // 16
    const int tx0 = (blockIdx.x % tilesX) * 32;
    const int ty0 = (blockIdx.x / tilesX) * 32;
    const int b = blockIdx.y;
    const int t = threadIdx.x;

    // dr+1 per b (digits b7..b0): 0,0,0,1,2,2,2,1 ; dc+1: 2,1,0,0,0,1,2,2
    const int dr = (int)((0x00012221u >> (b * 4)) & 15u) - 1;
    const int dc = (int)((0x21000122u >> (b * 4)) & 15u) - 1;

    // ---- phase 1: codes for tile+halo (34x34 items, width-34 walk)
    {
        int r = t / 34, cc = t % 34, idx = t;
#pragma unroll
        for (int it = 0; it < 5; ++it) {
            if (idx < 34 * 34) {
                int gi = ty0 - 1 + r, gj = tx0 - 1 + cc;
                unsigned char code = 0;
                if ((unsigned)gi < (unsigned)HH && (unsigned)gj < (unsigned)WW) {
                    size_t p0 = (size_t)gi * WW + gj;
                    int kp = KP[(size_t)b * HW + p0];
                    int kn = (kp + 4) & 7;
                    int ni = gi + dr, nj = gj + dc;
                    bool nin = ((unsigned)ni < (unsigned)HH) && ((unsigned)nj < (unsigned)WW);
                    size_t pn = (size_t)ni * WW + nj;
                    double gmp  = (double)GM[(size_t)kp * HW + p0];
                    double gmn  = (double)GM[(size_t)kn * HW + p0];
                    double gmpn = nin ? (double)GM[(size_t)kp * HW + pn] : 0.0;
                    double gmnn = nin ? (double)GM[(size_t)kn * HW + pn] : 0.0;
                    double pos = gmp - gmpn;
                    double neg = gmn - gmnn;
                    double thin = (fmin(pos, neg) > 0.0) ? (double)GM[(size_t)b * HW + p0] : 0.0;
                    if (thin > 0.3) code |= 1;
                    if (thin >= 0.1 && thin <= 0.3) code |= 2;
                }
                scode[r * 35 + cc] = code;
            }
            idx += 256; r += 7; cc += 18;        // 256 = 7*34 + 18
            if (cc >= 34) { cc -= 34; ++r; }
        }
    }
    __syncthreads();

    // ---- phase 2: hysteresis + border zero, 4 px/thread
#pragma unroll
    for (int p = 0; p < 4; ++p) {
        int pix = t + p * 256;
        int i = pix >> 5, j = pix & 31;
        int gi = ty0 + i, gj = tx0 + j;
        float res = 0.0f;
        if (gi > 0 && gi < HH - 1 && gj > 0 && gj < WW - 1) {
            const unsigned char* sc = scode + (i + 1) * 35 + (j + 1);
            unsigned char c = *sc;
            if (c & 1) {
                res = 1.0f;
            } else if (c & 2) {
                int any = 0;
                any |= sc[-36] & 1; any |= sc[-35] & 1; any |= sc[-34] & 1;
                any |= sc[-1]  & 1; any |= sc[ 1]  & 1;
                any |= sc[ 34] & 1; any |= sc[ 35] & 1; any |= sc[ 36] & 1;
                if (any) res = 1.0f;
            }
        }
        out[(size_t)b * HW + (size_t)gi * WW + gj] = res;
    }
}

extern "C" void kernel_launch(void* const* d_in, const int* in_sizes, int n_in,
                              void* d_out, int out_size, void* d_ws, size_t ws_size,
                              hipStream_t stream) {
    const float* img  = (const float*)d_in[0];
    const float* gwin = (const float*)d_in[1];

    float* GM = (float*)d_ws;                                   // 8 MB
    unsigned char* KP = (unsigned char*)d_ws + (size_t)NB * HW * sizeof(float);
    float* out = (float*)d_out;

    dim3 g1(NCOLS * (NROWS / WPB), NB);   // (144, 8) = 1152 blocks x 256 thr
    canny_gm_kernel<<<g1, 256, 0, stream>>>(img, gwin, GM, KP);

    dim3 g2((WW / 32) * (HH / 32), NB);   // (256, 8) blocks x 256
    canny_thin_out_kernel<<<g2, 256, 0, stream>>>(GM, KP, out);
}